// Round 16
// baseline (1397.915 us; speedup 1.0000x reference)
//
#include <hip/hip_runtime.h>

// ModalVerlet: B=16, M=64, T=48000. 1 scan + 2 storer waves (R13 skeleton).
//
// R16: 2-step COMPOSITION + even/odd chain decoupling.
// The step is affine in v=(z,u) apart from the lagged-r force:
//   v_{s+1} = M v_s + g(h_s),  M = [[a,b],[c,d]] constant per mode,
//   a = 1+CAGB*mom2C, b = CAu, c = mom2C, d = Fd,  g(h) = [CAGB*h, h],
//   h_s = phe*fe_s + g2 + m2g2*r   (r = rcp(exp2(z)+1), quad-rate, lag 2-8;
//                                   R15 passed absmax 2.0 with lag 5-8)
// Compose 2 steps with precomputed M^2:
//   z_{s+2} = A2 z + B2 u + E1 h_s + CAGB h_{s+1}
//   u_{s+2} = C2 z + D2 u + F1 h_s + h_{s+1}
//   A2=a^2+bc, B2=b(a+d), C2=c(a+d), D2=d^2+bc, E1=a*CAGB+b, F1=c*CAGB+d.
// Even chain (0,2,4,..) and odd chain (1,3,5,..) run as independent carried
// recurrences in the same lane: loop-carried depth = 1 fma per 2 time-steps
// per chain, chains fill each other's stalls. (R4-R15 showed ~45-50 cyc/step
// of distributed dependent-latency tax on the single-splice form; R14 showed
// a second independent chain fills stall slots.)
// Round n stores (ze,ue,zo,uo) = (z,u) at times (2n,2n+1) -> same LDS pair
// layout as R13; storers/p-reconstruction/w_kernel verbatim R13.

#define NB 16
#define NM 64
#define NT 48000
#define SPI 64
#define NITER (NT / SPI) // 750

__global__ void __launch_bounds__(192, 1) modal_scan_kernel(
    const float* __restrict__ y0,
    const float* __restrict__ omega,
    const float* __restrict__ sigma,
    const float* __restrict__ gamma,
    const float* __restrict__ Phi_e,
    const float* __restrict__ fe_points,
    float* __restrict__ y_out)
{
    const int b   = blockIdx.x;
    const int wid = threadIdx.x >> 6;
    const int m   = threadIdx.x & 63;

    __shared__ float4 lzu[2][SPI / 2][NM]; // per slot: (z_s,u_s,z_{s+1},u_{s+1}); 64KB
    __shared__ float  lub[2][NM];          // boundary u at tile end

    const float k    = 1.0f / 48000.0f;
    const float k2   = 0.5f * k;
    const float invC = 0.34657359027997264f; // ln(2)/2

    if (wid == 0) {
        // ---------------- scan wave ----------------
        const float om  = omega[b * NM + m];
        const float sg  = sigma[b * NM + m];
        const float g   = gamma[b];
        const float phe = Phi_e[b * NM + m];
        const float om2 = om * om;
        const float g2  = g * g;

        const float E    = 1.0f - k * sg;
        const float dinv = 1.0f / (1.0f + k * sg);
        const float A    = k * E;
        const float Bc   = k * k2;
        const float Fd   = E * dinv;
        const float Gd   = k2 * dinv;
        const float AGB  = A * Gd + Bc;
        const float m2g2 = -2.0f * g2;

        const float C    = 2.885390081777927f;   // 2*log2(e)
        const float CAGB = C * AGB;
        const float mom2C = -om2 * invC;
        const float GdF1 = Gd * (1.0f + Fd);
        const float CAu  = (C * A) * GdF1;

        // composed-map coefficients
        const float aM = fmaf(CAGB, mom2C, 1.0f);
        const float bM = CAu;
        const float cM = mom2C;
        const float dM = Fd;
        const float bc = bM * cM;
        const float A2 = fmaf(aM, aM, bc);
        const float B2 = bM * (aM + dM);
        const float C2 = cM * (aM + dM);
        const float D2 = fmaf(dM, dM, bc);
        const float E1 = fmaf(aM, CAGB, bM);
        const float F1 = fmaf(cM, CAGB, dM);

        const float q0v = y0[b * 2 * NM + m];
        const float p0v = y0[b * 2 * NM + NM + m];

        const float4* fe4 = reinterpret_cast<const float4*>(fe_points + (size_t)b * NT);

        float4 bufA[8], bufB[8];
#pragma unroll
        for (int i = 0; i < 8; ++i) bufA[i] = fe4[i];      // fe[0..31]
#pragma unroll
        for (int i = 0; i < 8; ++i) bufB[i] = fe4[8 + i];  // fe[32..63]

        // ---- preamble: states 0 (even) and 1 (odd) + trans priming ----
        float ze = C * q0v;
        float eP = __builtin_amdgcn_exp2f(ze);
        float rC = __builtin_amdgcn_rcpf(eP + 1.0f);
        float hbase = fmaf(m2g2, rC, g2);
        float ue, zo, uo;
        {
            float h00 = fmaf(phe, bufA[0].x, hbase);
            float kl0 = fmaf(mom2C, ze, h00);
            ue = fmaf(-Gd, kl0, p0v) / GdF1;               // u_0
            zo = fmaf(CAGB, kl0, fmaf(CAu, ue, ze));       // z_1
            uo = fmaf(Fd, ue, kl0);                        // u_1
        }

        // COMP: one 2-step composite advance of chain (Z,U) with (H0,H1)
#define COMP(Z, U, H0, H1) {                              \
    float t1 = CAGB * (H1);                               \
    float hz = fmaf(E1, (H0), t1);                        \
    float hu = fmaf(F1, (H0), (H1));                      \
    float zN = fmaf(A2, (Z), fmaf(B2, (U), hz));          \
    float uN = fmaf(C2, (Z), fmaf(D2, (U), hu));          \
    (Z) = zN; (U) = uN; }

        // QUAD: 2 rounds = 4 time-steps; F = fe[4m..4m+3], FNX = fe[4m+4].
        // Round r stores (ze,ue,zo,uo) = states (4m+2r, 4m+2r+1) BEFORE advance.
#define QUAD(F, FNX, SP, TP) {                            \
    float h0 = fmaf(phe, (F).x, hbase);                   \
    float h1 = fmaf(phe, (F).y, hbase);                   \
    float h2 = fmaf(phe, (F).z, hbase);                   \
    float h3 = fmaf(phe, (F).w, hbase);                   \
    float h4 = fmaf(phe, (FNX), hbase);                   \
    float aT = eP + 1.0f;                                 \
    (SP)[(TP) * NM] = make_float4(ze, ue, zo, uo);        \
    COMP(ze, ue, h0, h1);                                 \
    COMP(zo, uo, h1, h2);                                 \
    float rN = __builtin_amdgcn_rcpf(aT);                 \
    float eN = __builtin_amdgcn_exp2f(ze);                \
    (SP)[((TP) + 1) * NM] = make_float4(ze, ue, zo, uo);  \
    COMP(ze, ue, h2, h3);                                 \
    COMP(zo, uo, h3, h4);                                 \
    eP = eN; rC = rN;                                     \
    hbase = fmaf(m2g2, rC, g2); }

#define QUAD8(BUF, BNX, SP, TPB) \
    QUAD(BUF[0], BUF[1].x, SP, (TPB) + 0);  QUAD(BUF[1], BUF[2].x, SP, (TPB) + 2);  \
    QUAD(BUF[2], BUF[3].x, SP, (TPB) + 4);  QUAD(BUF[3], BUF[4].x, SP, (TPB) + 6);  \
    QUAD(BUF[4], BUF[5].x, SP, (TPB) + 8);  QUAD(BUF[5], BUF[6].x, SP, (TPB) + 10); \
    QUAD(BUF[6], BUF[7].x, SP, (TPB) + 12); QUAD(BUF[7], (BNX),    SP, (TPB) + 14);

#define TILE(JT, SP) {                                            \
    const int jn = ((JT) + 1 < NITER) ? ((JT) + 1) : (JT);        \
    QUAD8(bufA, bufB[0].x, SP, 0);                                \
    _Pragma("unroll")                                             \
    for (int i = 0; i < 8; ++i) bufA[i] = fe4[16 * jn + i];       \
    QUAD8(bufB, bufA[0].x, SP, 16);                               \
    _Pragma("unroll")                                             \
    for (int i = 0; i < 8; ++i) bufB[i] = fe4[16 * jn + 8 + i];   \
    lub[(JT) & 1][m] = ue;                                        \
    __syncthreads(); }

        float4* sp0 = &lzu[0][0][m];
        float4* sp1 = &lzu[1][0][m];
        for (int j = 0; j < NITER; j += 2) {
            TILE(j, sp0);
            TILE(j + 1, sp1);
        }
#undef TILE
#undef QUAD8
#undef QUAD
#undef COMP
    } else {
        // ---------------- storer waves (wpar = 0,1) ----------------
        const int wpar = wid - 1;
        const float sg   = sigma[b * NM + m];
        const float dinv = 1.0f / (1.0f + k * sg);
        const float Gd   = k2 * dinv;

        float* yql = y_out + ((size_t)b * 2 * NM + m) * (size_t)NT;
        float* ypl = yql + (size_t)NM * NT;

        for (int j = 0; j < NITER; ++j) {
            __syncthreads();            // publishes tile j (slot j&1) + lub
            if ((j & 1) != wpar) continue;

            const float4* sp = &lzu[j & 1][0][m];
            const float  ulast = lub[j & 1][m];
            float4* dq = reinterpret_cast<float4*>(yql + (size_t)SPI * j);
            float4* dp = reinterpret_cast<float4*>(ypl + (size_t)SPI * j);
#pragma unroll
            for (int i = 0; i < 16; ++i) {
                float4 va = sp[(2 * i) * NM];
                float4 vb = sp[(2 * i + 1) * NM];
                float  u2 = (i < 15) ? sp[(2 * i + 2) * NM].y : ulast;
                dq[i] = make_float4(invC * va.x, invC * va.z,
                                    invC * vb.x, invC * vb.z);
                dp[i] = make_float4(Gd * (va.y + va.w), Gd * (va.w + vb.y),
                                    Gd * (vb.y + vb.w), Gd * (vb.w + u2));
            }
        }
    }
}

// w[b,t] = sum_m Phi_o[b,m] * y[b,m,t]  (fully parallel, memory/L3-bound)
__global__ void __launch_bounds__(256) w_kernel(
    const float* __restrict__ y,
    const float* __restrict__ Phi_o,
    float* __restrict__ w)
{
    const int b  = blockIdx.y;
    const int t4 = blockIdx.x * 256 + threadIdx.x;
    if (t4 >= NT / 4) return;

    const float4* yb = reinterpret_cast<const float4*>(y + (size_t)b * 2 * NM * NT);
    const float*  po = Phi_o + b * NM;

    float4 acc = make_float4(0.f, 0.f, 0.f, 0.f);
    #pragma unroll 8
    for (int mm = 0; mm < NM; ++mm) {
        float  c = po[mm];
        float4 v = yb[mm * (NT / 4) + t4];
        acc.x = fmaf(c, v.x, acc.x);
        acc.y = fmaf(c, v.y, acc.y);
        acc.z = fmaf(c, v.z, acc.z);
        acc.w = fmaf(c, v.w, acc.w);
    }
    reinterpret_cast<float4*>(w + (size_t)b * NT)[t4] = acc;
}

extern "C" void kernel_launch(void* const* d_in, const int* in_sizes, int n_in,
                              void* d_out, int out_size, void* d_ws, size_t ws_size,
                              hipStream_t stream)
{
    // inputs: 0=fs, 1=num_samples, 2=y0, 3=omega, 4=sigma, 5=gamma,
    //         6=Phi_e, 7=Phi_o, 8=fe_points
    const float* y0    = (const float*)d_in[2];
    const float* omega = (const float*)d_in[3];
    const float* sigma = (const float*)d_in[4];
    const float* gamma = (const float*)d_in[5];
    const float* Phi_e = (const float*)d_in[6];
    const float* Phi_o = (const float*)d_in[7];
    const float* fe    = (const float*)d_in[8];

    float* y_out = (float*)d_out;                    // (B, 2M, T)
    float* w_out = y_out + (size_t)NB * 2 * NM * NT; // (B, T)

    modal_scan_kernel<<<NB, 192, 0, stream>>>(y0, omega, sigma, gamma, Phi_e, fe, y_out);

    dim3 grid((NT / 4 + 255) / 256, NB);
    w_kernel<<<grid, 256, 0, stream>>>(y_out, Phi_o, w_out);
}

// Round 17
// 1249.498 us; speedup vs baseline: 1.1188x; 1.1188x over previous
//
#include <hip/hip_runtime.h>

// ModalVerlet: B=16, M=64, T=48000. 1 scan + 2 storer waves (R13 skeleton).
//
// R17: z-ONLY LDS publication. Key identity of the affine step
//   z_{s+1} = z_s + CAu*u_s + CAGB*kl_s,  u_{s+1} = Fd*u_s + kl_s,
//   with CAu/CAGB == Fd exactly  =>  u_{s+1} = (z_{s+1} - z_s)/CAGB
//   =>  p_s = Gd*(u_s+u_{s+1}) = (Gd/CAGB)*(z_{s+1} - z_{s-1}).
// So the scan stores ONE float4 of z per 4 steps (was 2x (z,u) pairs):
// ds_write data-register reuse distance grows ~36 -> ~75+ cyc (>= LDS write
// completion), removing the lgkmcnt recycle stall that R4-R16's flat ~50
// cyc/step base is attributed to. Storer reconstructs q = invC*z and
// p = GdiC*(z_next - z_prev) (central difference; boundary z's via lub:
// lub[slot] = (z_{tilestart-1}, z_{tilestart+64}); z_{-1} := z_0 - CAGB*u_0).
//
// Scan math verbatim R16 (absmax 2.0): composed 2-step map on even/odd
// chains, quad-rate trans refresh (r lag 2-8 steps).

#define NB 16
#define NM 64
#define NT 48000
#define SPI 64
#define NITER (NT / SPI) // 750

__global__ void __launch_bounds__(192, 1) modal_scan_kernel(
    const float* __restrict__ y0,
    const float* __restrict__ omega,
    const float* __restrict__ sigma,
    const float* __restrict__ gamma,
    const float* __restrict__ Phi_e,
    const float* __restrict__ fe_points,
    float* __restrict__ y_out)
{
    const int b   = blockIdx.x;
    const int wid = threadIdx.x >> 6;
    const int m   = threadIdx.x & 63;

    __shared__ float4 lz[2][SPI / 4][NM];  // z quads; 32 KB
    __shared__ float2 lub[2][NM];          // (z_{start-1}, z_{end}) per tile

    const float k    = 1.0f / 48000.0f;
    const float k2   = 0.5f * k;
    const float invC = 0.34657359027997264f; // ln(2)/2
    const float Cc   = 2.885390081777927f;   // 2*log2(e)

    if (wid == 0) {
        // ---------------- scan wave ----------------
        const float om  = omega[b * NM + m];
        const float sg  = sigma[b * NM + m];
        const float g   = gamma[b];
        const float phe = Phi_e[b * NM + m];
        const float om2 = om * om;
        const float g2  = g * g;

        const float E    = 1.0f - k * sg;
        const float dinv = 1.0f / (1.0f + k * sg);
        const float A    = k * E;
        const float Bc   = k * k2;
        const float Fd   = E * dinv;
        const float Gd   = k2 * dinv;
        const float AGB  = A * Gd + Bc;
        const float m2g2 = -2.0f * g2;

        const float CAGB = Cc * AGB;
        const float mom2C = -om2 * invC;
        const float GdF1 = Gd * (1.0f + Fd);
        const float CAu  = (Cc * A) * GdF1;

        // composed-map coefficients
        const float aM = fmaf(CAGB, mom2C, 1.0f);
        const float bM = CAu;
        const float cM = mom2C;
        const float dM = Fd;
        const float bc = bM * cM;
        const float A2 = fmaf(aM, aM, bc);
        const float B2 = bM * (aM + dM);
        const float C2 = cM * (aM + dM);
        const float D2 = fmaf(dM, dM, bc);
        const float E1 = fmaf(aM, CAGB, bM);
        const float F1 = fmaf(cM, CAGB, dM);

        const float q0v = y0[b * 2 * NM + m];
        const float p0v = y0[b * 2 * NM + NM + m];

        const float4* fe4 = reinterpret_cast<const float4*>(fe_points + (size_t)b * NT);

        float4 bufA[8], bufB[8];
#pragma unroll
        for (int i = 0; i < 8; ++i) bufA[i] = fe4[i];      // fe[0..31]
#pragma unroll
        for (int i = 0; i < 8; ++i) bufB[i] = fe4[8 + i];  // fe[32..63]

        // ---- preamble: states 0 (even) and 1 (odd) + trans priming ----
        float ze = Cc * q0v;
        float eP = __builtin_amdgcn_exp2f(ze);
        float rC = __builtin_amdgcn_rcpf(eP + 1.0f);
        float hbase = fmaf(m2g2, rC, g2);
        float ue, zo, uo, zm1, zql = 0.0f;
        {
            float h00 = fmaf(phe, bufA[0].x, hbase);
            float kl0 = fmaf(mom2C, ze, h00);
            ue = fmaf(-Gd, kl0, p0v) / GdF1;               // u_0
            zo = fmaf(CAGB, kl0, fmaf(CAu, ue, ze));       // z_1
            uo = fmaf(Fd, ue, kl0);                        // u_1
            zm1 = fmaf(-CAGB, ue, ze);                     // synthetic z_{-1}
        }

        // COMP: one 2-step composite advance of chain (Z,U) with (H0,H1)
#define COMP(Z, U, H0, H1) {                              \
    float t1 = CAGB * (H1);                               \
    float hz = fmaf(E1, (H0), t1);                        \
    float hu = fmaf(F1, (H0), (H1));                      \
    float zN = fmaf(A2, (Z), fmaf(B2, (U), hz));          \
    float uN = fmaf(C2, (Z), fmaf(D2, (U), hu));          \
    (Z) = zN; (U) = uN; }

        // QUAD m: 4 time-steps; stores (z_{4m},z_{4m+1},z_{4m+2},z_{4m+3}).
#define QUAD(F, FNX, SP, TP) {                            \
    float h0 = fmaf(phe, (F).x, hbase);                   \
    float h1 = fmaf(phe, (F).y, hbase);                   \
    float h2 = fmaf(phe, (F).z, hbase);                   \
    float h3 = fmaf(phe, (F).w, hbase);                   \
    float h4 = fmaf(phe, (FNX), hbase);                   \
    float aT = eP + 1.0f;                                 \
    float za = ze, zb = zo;                               \
    COMP(ze, ue, h0, h1);                                 \
    COMP(zo, uo, h1, h2);                                 \
    float rN = __builtin_amdgcn_rcpf(aT);                 \
    float eN = __builtin_amdgcn_exp2f(ze);                \
    (SP)[(TP) * NM] = make_float4(za, zb, ze, zo);        \
    zql = zo;                                             \
    COMP(ze, ue, h2, h3);                                 \
    COMP(zo, uo, h3, h4);                                 \
    eP = eN; rC = rN;                                     \
    hbase = fmaf(m2g2, rC, g2); }

#define QUAD8(BUF, BNX, SP, TPB) \
    QUAD(BUF[0], BUF[1].x, SP, (TPB) + 0);  QUAD(BUF[1], BUF[2].x, SP, (TPB) + 1);  \
    QUAD(BUF[2], BUF[3].x, SP, (TPB) + 2);  QUAD(BUF[3], BUF[4].x, SP, (TPB) + 3);  \
    QUAD(BUF[4], BUF[5].x, SP, (TPB) + 4);  QUAD(BUF[5], BUF[6].x, SP, (TPB) + 5);  \
    QUAD(BUF[6], BUF[7].x, SP, (TPB) + 6);  QUAD(BUF[7], (BNX),    SP, (TPB) + 7);

#define TILE(JT, SP) {                                            \
    const int jn = ((JT) + 1 < NITER) ? ((JT) + 1) : (JT);        \
    QUAD8(bufA, bufB[0].x, SP, 0);                                \
    _Pragma("unroll")                                             \
    for (int i = 0; i < 8; ++i) bufA[i] = fe4[16 * jn + i];       \
    QUAD8(bufB, bufA[0].x, SP, 8);                                \
    _Pragma("unroll")                                             \
    for (int i = 0; i < 8; ++i) bufB[i] = fe4[16 * jn + 8 + i];   \
    lub[(JT) & 1][m] = make_float2(zm1, ze);                      \
    zm1 = zql;                                                    \
    __syncthreads(); }

        float4* sp0 = &lz[0][0][m];
        float4* sp1 = &lz[1][0][m];
        for (int j = 0; j < NITER; j += 2) {
            TILE(j, sp0);
            TILE(j + 1, sp1);
        }
#undef TILE
#undef QUAD8
#undef QUAD
#undef COMP
    } else {
        // ---------------- storer waves (wpar = 0,1) ----------------
        const int wpar = wid - 1;
        const float sg   = sigma[b * NM + m];
        const float E    = 1.0f - k * sg;
        const float dinv = 1.0f / (1.0f + k * sg);
        const float A    = k * E;
        const float Bc   = k * k2;
        const float Gd   = k2 * dinv;
        const float AGB  = A * Gd + Bc;
        const float CAGB = Cc * AGB;
        const float GdiC = Gd / CAGB;   // p_s = GdiC*(z_{s+1} - z_{s-1})

        float* yql = y_out + ((size_t)b * 2 * NM + m) * (size_t)NT;
        float* ypl = yql + (size_t)NM * NT;

        for (int j = 0; j < NITER; ++j) {
            __syncthreads();            // publishes tile j (slot j&1) + lub
            if ((j & 1) != wpar) continue;

            const float4* sp = &lz[j & 1][0][m];
            const float2 bz = lub[j & 1][m];   // (z_{start-1}, z_{end})
            float4* dq = reinterpret_cast<float4*>(yql + (size_t)SPI * j);
            float4* dp = reinterpret_cast<float4*>(ypl + (size_t)SPI * j);

            float  zpw = bz.x;
            float4 cur = sp[0];
#pragma unroll
            for (int i = 0; i < 16; ++i) {
                float4 nxt = (i < 15) ? sp[(i + 1) * NM]
                                      : make_float4(bz.y, 0.f, 0.f, 0.f);
                dq[i] = make_float4(invC * cur.x, invC * cur.y,
                                    invC * cur.z, invC * cur.w);
                dp[i] = make_float4(GdiC * (cur.y - zpw),
                                    GdiC * (cur.z - cur.x),
                                    GdiC * (cur.w - cur.y),
                                    GdiC * (nxt.x - cur.z));
                zpw = cur.w;
                cur = nxt;
            }
        }
    }
}

// w[b,t] = sum_m Phi_o[b,m] * y[b,m,t]  (fully parallel, memory/L3-bound)
__global__ void __launch_bounds__(256) w_kernel(
    const float* __restrict__ y,
    const float* __restrict__ Phi_o,
    float* __restrict__ w)
{
    const int b  = blockIdx.y;
    const int t4 = blockIdx.x * 256 + threadIdx.x;
    if (t4 >= NT / 4) return;

    const float4* yb = reinterpret_cast<const float4*>(y + (size_t)b * 2 * NM * NT);
    const float*  po = Phi_o + b * NM;

    float4 acc = make_float4(0.f, 0.f, 0.f, 0.f);
    #pragma unroll 8
    for (int mm = 0; mm < NM; ++mm) {
        float  c = po[mm];
        float4 v = yb[mm * (NT / 4) + t4];
        acc.x = fmaf(c, v.x, acc.x);
        acc.y = fmaf(c, v.y, acc.y);
        acc.z = fmaf(c, v.z, acc.z);
        acc.w = fmaf(c, v.w, acc.w);
    }
    reinterpret_cast<float4*>(w + (size_t)b * NT)[t4] = acc;
}

extern "C" void kernel_launch(void* const* d_in, const int* in_sizes, int n_in,
                              void* d_out, int out_size, void* d_ws, size_t ws_size,
                              hipStream_t stream)
{
    // inputs: 0=fs, 1=num_samples, 2=y0, 3=omega, 4=sigma, 5=gamma,
    //         6=Phi_e, 7=Phi_o, 8=fe_points
    const float* y0    = (const float*)d_in[2];
    const float* omega = (const float*)d_in[3];
    const float* sigma = (const float*)d_in[4];
    const float* gamma = (const float*)d_in[5];
    const float* Phi_e = (const float*)d_in[6];
    const float* Phi_o = (const float*)d_in[7];
    const float* fe    = (const float*)d_in[8];

    float* y_out = (float*)d_out;                    // (B, 2M, T)
    float* w_out = y_out + (size_t)NB * 2 * NM * NT; // (B, T)

    modal_scan_kernel<<<NB, 192, 0, stream>>>(y0, omega, sigma, gamma, Phi_e, fe, y_out);

    dim3 grid((NT / 4 + 255) / 256, NB);
    w_kernel<<<grid, 256, 0, stream>>>(y_out, Phi_o, w_out);
}